// Round 9
// baseline (127.987 us; speedup 1.0000x reference)
//
#include <hip/hip_runtime.h>
#include <math.h>

// ---------------------------------------------------------------------------
// SpatialProximityHead on MI355X — round 8: round-7 pipeline with the
// oprojln B-fragment addressing fix (missing lk k-offset).
// 13 dispatches, barrier-free MFMA GEMMs reading bf16 directly from global.
// ---------------------------------------------------------------------------

#define NTOK 512
#define HDIM 256
#define DKH  64
#define NHEAD 4
#define TLEN 6
#define WSZ  65536   // elements per 256x256 weight matrix

typedef __attribute__((ext_vector_type(8))) short bf16x8;
typedef __attribute__((ext_vector_type(4))) float f32x4;

__device__ __forceinline__ ushort f2bf(float f)
{
    unsigned u = __builtin_bit_cast(unsigned, f);
    u += 0x7FFFu + ((u >> 16) & 1u);     // RNE
    return (ushort)(u >> 16);
}

struct PKArg {
    const float* w[13];
    const float* qf; const float* pl;
    ushort* wpk; ushort* qf16;
    float *dist, *dwraw, *inv_cs;
};

// ---------------------------------------------------------------------------
// pack: blocks 0-207 = weight 64x64 transpose tiles (13 mats x 16 tiles);
// 208-223 = qf -> bf16 straight cast; 224-231 = dist/dwraw/inv_cs prep.
// ---------------------------------------------------------------------------
__global__ __launch_bounds__(256) void pack_kernel(PKArg p)
{
    __shared__ __align__(16) ushort smu[64 * 72];   // transpose buffer
    const int bid = blockIdx.x;
    const int t   = threadIdx.x;

    if (bid < 208) {
        const int mat  = bid >> 4;
        const int tile = bid & 15;
        const int k0   = (tile >> 2) * 64;
        const int c0   = (tile & 3) * 64;
        const float* W = p.w[mat];
#pragma unroll
        for (int j = 0; j < 4; ++j) {
            const int i  = t + j * 256;        // 0..1023 = 64 rows x 16 f4
            const int r  = i >> 4, c4 = i & 15;
            const float4 v4 = *(const float4*)&W[(k0 + r) * HDIM + c0 + c4 * 4];
            smu[(c4 * 4 + 0) * 72 + r] = f2bf(v4.x);
            smu[(c4 * 4 + 1) * 72 + r] = f2bf(v4.y);
            smu[(c4 * 4 + 2) * 72 + r] = f2bf(v4.z);
            smu[(c4 * 4 + 3) * 72 + r] = f2bf(v4.w);
        }
        __syncthreads();
#pragma unroll
        for (int j = 0; j < 2; ++j) {
            const int i  = t + j * 256;        // 0..511 = 64 cols x 8 u16x8
            const int cr = i >> 3, kk = i & 7;
            const uint4 v = *(const uint4*)&smu[cr * 72 + kk * 8];
            *(uint4*)&p.wpk[mat * WSZ + (c0 + cr) * HDIM + k0 + kk * 8] = v;
        }
    } else if (bid < 224) {
        const int r0 = (bid - 208) * 32;
#pragma unroll
        for (int j = 0; j < 8; ++j) {
            const int i  = t + j * 256;        // 0..2047 = 32 rows x 64 f4
            const int r  = i >> 6, c4 = i & 63;
            const float4 v4 = *(const float4*)&p.qf[(r0 + r) * HDIM + c4 * 4];
            ushort4 s = {f2bf(v4.x), f2bf(v4.y), f2bf(v4.z), f2bf(v4.w)};
            *(ushort4*)&p.qf16[(r0 + r) * HDIM + c4 * 4] = s;
        }
    } else {
        float* smf = (float*)smu;
        float* qe  = smf;            // [512][3]
        float* red = smf + 1536;     // [4][64]
        const int item = bid - 224;
        for (int i = t; i < 512; i += 256) {
            qe[i * 3 + 0] = p.pl[i * 33 + 30];
            qe[i * 3 + 1] = p.pl[i * 33 + 31];
            qe[i * 3 + 2] = p.pl[i * 33 + 32];
        }
        __syncthreads();
        const int m   = item * 64 + (t & 63);
        const int nch = t >> 6;
        const float kx = p.pl[m * 33 + 0], ky = p.pl[m * 33 + 1], kz = p.pl[m * 33 + 2];
        float cs = 0.f;
        for (int n = nch * 128; n < nch * 128 + 128; ++n) {
            const float dx = kx - qe[n * 3 + 0];
            const float dy = ky - qe[n * 3 + 1];
            const float dz = kz - qe[n * 3 + 2];
            const float dd = sqrtf(dx * dx + dy * dy + dz * dz);
            const float w  = 1.0f / (dd + 0.01f);
            p.dist[n * NTOK + m]  = dd;
            p.dwraw[n * NTOK + m] = w;
            cs += w;
        }
        red[nch * 64 + (t & 63)] = cs;
        __syncthreads();
        if (t < 64)
            p.inv_cs[item * 64 + t] =
                1.0f / (red[t] + red[64 + t] + red[128 + t] + red[192 + t]);
    }
}

// ---------------------------------------------------------------------------
// gemm_bf: C(512x256) = A16(512x256 bf16) @ Wt(bf16 [col][k]) + b.
// Barrier-free: wave = 16 rows x 64 cols, K=256. 32 blocks per problem.
// ---------------------------------------------------------------------------
struct GB { const ushort* A16; const ushort* Wt; const float* b;
            float* C; ushort* C16; };

__global__ __launch_bounds__(256) void gemm_bf(GB g0, GB g1, GB g2, int relu)
{
    const int bid = blockIdx.x;
    const GB g = (bid < 32) ? g0 : (bid < 64) ? g1 : g2;
    const int t = threadIdx.x;
    const int wv = t >> 6, lane = t & 63;
    const int gw = (bid & 31) * 4 + wv;        // 0..127
    const int rg = gw >> 2, cg = gw & 3;       // 32 row-groups x 4 col-groups
    const int lr = lane & 15, lk = (lane >> 4) * 8;

    const ushort* Arow = g.A16 + (rg * 16 + lr) * HDIM + lk;
    const ushort* Wrow = g.Wt + (cg * 64 + lr) * HDIM + lk;

    f32x4 acc[4];
#pragma unroll
    for (int j = 0; j < 4; ++j) acc[j] = (f32x4){0.f, 0.f, 0.f, 0.f};

#pragma unroll
    for (int ks = 0; ks < 8; ++ks) {
        const bf16x8 a = *(const bf16x8*)&Arow[ks * 32];
#pragma unroll
        for (int j = 0; j < 4; ++j) {
            const bf16x8 b = *(const bf16x8*)&Wrow[j * 16 * HDIM + ks * 32];
            acc[j] = __builtin_amdgcn_mfma_f32_16x16x32_bf16(a, b, acc[j], 0, 0, 0);
        }
    }

    const int orow = rg * 16 + (lane >> 4) * 4;
#pragma unroll
    for (int j = 0; j < 4; ++j) {
        const int col = cg * 64 + j * 16 + lr;
        const float bb = g.b ? g.b[col] : 0.f;
#pragma unroll
        for (int r = 0; r < 4; ++r) {
            float o = acc[j][r] + bb;
            if (relu) o = fmaxf(o, 0.f);
            if (g.C)   g.C[(orow + r) * HDIM + col] = o;
            if (g.C16) g.C16[(orow + r) * HDIM + col] = f2bf(o);
        }
    }
}

// ---------------------------------------------------------------------------
// qkt_bf: S[h][n][m] = q.k^T/8 + bias. Barrier-free; wave = 16n x 64m.
// grid 256 blocks: h = bid>>6, ng = (bid>>1)&31, mh = bid&1.
// ---------------------------------------------------------------------------
__global__ __launch_bounds__(256) void qkt_bf(
    const ushort* __restrict__ q16, const ushort* __restrict__ k16,
    const float* __restrict__ dist, const float* __restrict__ dwraw,
    const float* __restrict__ inv_cs, float* __restrict__ S)
{
    const int bid = blockIdx.x;
    const int h  = bid >> 6;
    const int ng = (bid >> 1) & 31;
    const int mh = bid & 1;
    const int t  = threadIdx.x;
    const int wv = t >> 6, lane = t & 63;
    const int m0 = mh * 256 + wv * 64;
    const int lr = lane & 15, lk = (lane >> 4) * 8;

    const ushort* Qrow = q16 + (ng * 16 + lr) * HDIM + h * DKH + lk;
    const ushort* Krow = k16 + (m0 + lr) * HDIM + h * DKH + lk;

    f32x4 acc[4];
#pragma unroll
    for (int j = 0; j < 4; ++j) acc[j] = (f32x4){0.f, 0.f, 0.f, 0.f};

#pragma unroll
    for (int ks = 0; ks < 2; ++ks) {
        const bf16x8 a = *(const bf16x8*)&Qrow[ks * 32];
#pragma unroll
        for (int j = 0; j < 4; ++j) {
            const bf16x8 b = *(const bf16x8*)&Krow[j * 16 * HDIM + ks * 32];
            acc[j] = __builtin_amdgcn_mfma_f32_16x16x32_bf16(a, b, acc[j], 0, 0, 0);
        }
    }

    const int orow = ng * 16 + (lane >> 4) * 4;
#pragma unroll
    for (int j = 0; j < 4; ++j) {
        const int m = m0 + j * 16 + lr;
        const float ic = (h == 0) ? inv_cs[m] : 0.f;
#pragma unroll
        for (int r = 0; r < 4; ++r) {
            const int n = orow + r;
            float bias = 0.f;
            if (h == 0)      bias = dwraw[n * NTOK + m] * ic;
            else if (h == 1) bias = -dist[n * NTOK + m];
            S[(h * NTOK + n) * NTOK + m] = acc[j][r] * 0.125f + bias;
        }
    }
}

// ---------------------------------------------------------------------------
// smpv: fused softmax + full-K P@V for 8 q-rows of one head. grid (64,4).
// Writes ao16 (bf16).
// ---------------------------------------------------------------------------
__global__ __launch_bounds__(256) void smpv_kernel(
    const float* __restrict__ S, const float* __restrict__ v,
    ushort* __restrict__ ao16)
{
    __shared__ float ps[NTOK * 10];
    __shared__ float ri[8];
    __shared__ __align__(16) float exch[4 * 8 * 16 * 4];

    const int h  = blockIdx.y;
    const int n0 = blockIdx.x * 8;
    const int t  = threadIdx.x;

    {   // softmax
        const int row = t >> 5, j = t & 31;
        const float* Srow = S + (h * NTOK + n0 + row) * NTOK;
        float vals[16];
        float mx = -1e30f;
#pragma unroll
        for (int u = 0; u < 16; ++u) {
            vals[u] = Srow[j + u * 32];
            mx = fmaxf(mx, vals[u]);
        }
#pragma unroll
        for (int o = 16; o; o >>= 1) mx = fmaxf(mx, __shfl_xor(mx, o, 32));
        float sum = 0.f;
#pragma unroll
        for (int u = 0; u < 16; ++u) {
            const float e = __expf(vals[u] - mx);
            vals[u] = e;
            sum += e;
        }
#pragma unroll
        for (int o = 16; o; o >>= 1) sum += __shfl_xor(sum, o, 32);
        if (j == 0) ri[row] = 1.0f / sum;
#pragma unroll
        for (int u = 0; u < 16; ++u)
            ps[(j + u * 32) * 10 + row] = vals[u];
    }
    __syncthreads();

    const int tx = t & 15, rp = (t >> 4) & 3, kh = t >> 6;
    const int r0 = rp * 2;
    const float* vb = v + (kh * 128) * HDIM + h * DKH + tx * 4;
    f32x4 a0 = {0.f, 0.f, 0.f, 0.f}, a1 = {0.f, 0.f, 0.f, 0.f};
#pragma unroll 8
    for (int kk = 0; kk < 128; ++kk) {
        const float4 vv = *(const float4*)&vb[kk * HDIM];
        const float2 pp = *(const float2*)&ps[(kh * 128 + kk) * 10 + r0];
        a0.x += pp.x * vv.x; a0.y += pp.x * vv.y;
        a0.z += pp.x * vv.z; a0.w += pp.x * vv.w;
        a1.x += pp.y * vv.x; a1.y += pp.y * vv.y;
        a1.z += pp.y * vv.z; a1.w += pp.y * vv.w;
    }
    if (kh > 0) {
        *(f32x4*)&exch[((kh * 8 + r0) * 16 + tx) * 4]     = a0;
        *(f32x4*)&exch[((kh * 8 + r0 + 1) * 16 + tx) * 4] = a1;
    }
    __syncthreads();
    if (kh == 0) {
#pragma unroll
        for (int kk = 1; kk < 4; ++kk) {
            a0 += *(const f32x4*)&exch[((kk * 8 + r0) * 16 + tx) * 4];
            a1 += *(const f32x4*)&exch[((kk * 8 + r0 + 1) * 16 + tx) * 4];
        }
        const float s0 = ri[r0], s1 = ri[r0 + 1];
        ushort4 o0 = {f2bf(a0.x * s0), f2bf(a0.y * s0), f2bf(a0.z * s0), f2bf(a0.w * s0)};
        ushort4 o1 = {f2bf(a1.x * s1), f2bf(a1.y * s1), f2bf(a1.z * s1), f2bf(a1.w * s1)};
        *(ushort4*)&ao16[(n0 + r0) * HDIM + h * DKH + tx * 4]     = o0;
        *(ushort4*)&ao16[(n0 + r0 + 1) * HDIM + h * DKH + tx * 4] = o1;
    }
}

// ---------------------------------------------------------------------------
// oprojln: one wave = 16 rows x all 256 cols. y = ao16@WoT + bo + x;
// LN in-register via shfl over 16-lane groups. Writes x (f32) and x16 (bf16).
// grid 32 blocks x 64 threads.
// ---------------------------------------------------------------------------
__global__ __launch_bounds__(64) void oprojln(
    const ushort* __restrict__ ao16, const ushort* __restrict__ WoT,
    const float* __restrict__ bo, const float* __restrict__ g,
    const float* __restrict__ bb, float* __restrict__ x,
    ushort* __restrict__ x16)
{
    const int rg = blockIdx.x;           // 16-row group
    const int lane = threadIdx.x;
    const int lr = lane & 15, lk = (lane >> 4) * 8;

    const ushort* Arow = ao16 + (rg * 16 + lr) * HDIM + lk;
    const ushort* Brow = WoT + lr * HDIM + lk;   // FIX: lk was missing (r7 bug)

    f32x4 acc[16];
#pragma unroll
    for (int j = 0; j < 16; ++j) acc[j] = (f32x4){0.f, 0.f, 0.f, 0.f};

#pragma unroll
    for (int ks = 0; ks < 8; ++ks) {
        const bf16x8 a = *(const bf16x8*)&Arow[ks * 32];
#pragma unroll
        for (int j = 0; j < 16; ++j) {
            const bf16x8 b = *(const bf16x8*)&Brow[j * 16 * HDIM + ks * 32];
            acc[j] = __builtin_amdgcn_mfma_f32_16x16x32_bf16(a, b, acc[j], 0, 0, 0);
        }
    }

    const int row0 = rg * 16 + (lane >> 4) * 4;
#pragma unroll
    for (int j = 0; j < 16; ++j) {
        const int col = j * 16 + lr;
        const float bc = bo[col];
#pragma unroll
        for (int r = 0; r < 4; ++r)
            acc[j][r] += bc + x[(row0 + r) * HDIM + col];
    }
    float mean[4], rstd[4];
#pragma unroll
    for (int r = 0; r < 4; ++r) {
        float s = 0.f;
#pragma unroll
        for (int j = 0; j < 16; ++j) s += acc[j][r];
#pragma unroll
        for (int o = 8; o; o >>= 1) s += __shfl_xor(s, o);
        mean[r] = s * (1.0f / 256.0f);
        float s2 = 0.f;
#pragma unroll
        for (int j = 0; j < 16; ++j) {
            const float c = acc[j][r] - mean[r];
            s2 += c * c;
        }
#pragma unroll
        for (int o = 8; o; o >>= 1) s2 += __shfl_xor(s2, o);
        rstd[r] = rsqrtf(s2 * (1.0f / 256.0f) + 1e-5f);
    }
#pragma unroll
    for (int j = 0; j < 16; ++j) {
        const int col = j * 16 + lr;
        const float gg = g[col], bv = bb[col];
#pragma unroll
        for (int r = 0; r < 4; ++r) {
            const float o = (acc[j][r] - mean[r]) * rstd[r] * gg + bv;
            x[(row0 + r) * HDIM + col]   = o;
            x16[(row0 + r) * HDIM + col] = f2bf(o);
        }
    }
}

// ---------------------------------------------------------------------------
// pair_cls: 32x32 tile, 2x2 per thread, TL copies. (f32 inputs)
// ---------------------------------------------------------------------------
__global__ __launch_bounds__(256) void pair_cls(const float* __restrict__ U1,
                                                const float* __restrict__ U2,
                                                const float* __restrict__ W2,
                                                const float* __restrict__ b2,
                                                float* __restrict__ out)
{
    __shared__ __align__(16) float u1s[32][260];
    __shared__ __align__(16) float u2s[32][260];
    __shared__ __align__(16) float w2s[256];
    const int t  = threadIdx.x;
    const int n0 = blockIdx.y * 32, m0 = blockIdx.x * 32;

    for (int i = t; i < 32 * 64; i += 256) {
        const int r = i >> 6, c4 = i & 63;
        *(float4*)&u1s[r][c4 * 4] = *(const float4*)&U1[(n0 + r) * HDIM + c4 * 4];
        *(float4*)&u2s[r][c4 * 4] = *(const float4*)&U2[(m0 + r) * HDIM + c4 * 4];
    }
    if (t < 64) *(float4*)&w2s[t * 4] = *(const float4*)&W2[t * 4];
    __syncthreads();

    const int tx = t & 15, ty = t >> 4;
    float acc[2][2] = {};
    for (int h4 = 0; h4 < 64; ++h4) {
        const float4 a0 = *(const float4*)&u1s[ty * 2][h4 * 4];
        const float4 a1 = *(const float4*)&u1s[ty * 2 + 1][h4 * 4];
        const float4 b0 = *(const float4*)&u2s[tx * 2][h4 * 4];
        const float4 b1 = *(const float4*)&u2s[tx * 2 + 1][h4 * 4];
        const float4 w  = *(const float4*)&w2s[h4 * 4];
#define RT(A, B) fmaxf((A) + (B), 0.f)
        acc[0][0] += RT(a0.x,b0.x)*w.x + RT(a0.y,b0.y)*w.y + RT(a0.z,b0.z)*w.z + RT(a0.w,b0.w)*w.w;
        acc[0][1] += RT(a0.x,b1.x)*w.x + RT(a0.y,b1.y)*w.y + RT(a0.z,b1.z)*w.z + RT(a0.w,b1.w)*w.w;
        acc[1][0] += RT(a1.x,b0.x)*w.x + RT(a1.y,b0.y)*w.y + RT(a1.z,b0.z)*w.z + RT(a1.w,b0.w)*w.w;
        acc[1][1] += RT(a1.x,b1.x)*w.x + RT(a1.y,b1.y)*w.y + RT(a1.z,b1.z)*w.z + RT(a1.w,b1.w)*w.w;
#undef RT
    }
    const float bbv = b2[0];
#pragma unroll
    for (int ii = 0; ii < 2; ++ii)
#pragma unroll
        for (int jj = 0; jj < 2; ++jj) {
            const float val = acc[ii][jj] + bbv;
            const int n = n0 + ty * 2 + ii;
            const int m = m0 + tx * 2 + jj;
#pragma unroll
            for (int tl = 0; tl < TLEN; ++tl)
                out[tl * NTOK * NTOK + n * NTOK + m] = val;
        }
}

// ---------------------------------------------------------------------------
extern "C" void kernel_launch(void* const* d_in, const int* in_sizes, int n_in,
                              void* d_out, int out_size, void* d_ws, size_t ws_size,
                              hipStream_t stream)
{
    const float* hs   = (const float*)d_in[0];
    const float* qf   = hs + 5 * NTOK * HDIM;
    const float* alp  = (const float*)d_in[1];
    const float* pl   = alp + 5 * NTOK * 33;
    const float* fc_W = (const float*)d_in[2];
    const float* fc_b = (const float*)d_in[3];
    const float* Wq   = (const float*)d_in[4];
    const float* bq   = (const float*)d_in[5];
    const float* Wk   = (const float*)d_in[6];
    const float* bk   = (const float*)d_in[7];
    const float* Wv   = (const float*)d_in[8];
    const float* bv   = (const float*)d_in[9];
    const float* Wo   = (const float*)d_in[10];
    const float* bo   = (const float*)d_in[11];
    const float* lng  = (const float*)d_in[12];
    const float* lnb  = (const float*)d_in[13];
    const float* m1W  = (const float*)d_in[14];
    const float* m1b  = (const float*)d_in[15];
    const float* m2W  = (const float*)d_in[16];
    const float* m2b  = (const float*)d_in[17];
    const float* cW1  = (const float*)d_in[18];
    const float* cb1  = (const float*)d_in[19];
    const float* cW2  = (const float*)d_in[20];
    const float* cb2  = (const float*)d_in[21];
    float* out = (float*)d_out;

    const int NN  = NTOK * NTOK;
    const int NH_ = NTOK * HDIM;
    float* ws     = (float*)d_ws;
    float* dist   = ws;                       // NN
    float* dwraw  = ws + NN;                  // NN
    float* inv_cs = ws + 2 * NN;              // 512
    float* x      = ws + 2 * NN + 512;        // NH
    float* v      = x + NH_;                  // NH
    float* U1     = v + NH_;                  // NH
    float* U2     = U1 + NH_;                 // NH
    float* S      = U2 + NH_;                 // 4*NN
    ushort* u16   = (ushort*)(S + 4 * NN);
    ushort* wpk   = u16;                      // 13 * WSZ
    ushort* qf16  = wpk + 13 * WSZ;           // NH
    ushort* x16   = qf16 + NH_;               // NH
    ushort* q16   = x16 + NH_;                // NH
    ushort* k16   = q16 + NH_;                // NH
    ushort* ao16  = k16 + NH_;                // NH
    ushort* o116  = ao16 + NH_;               // NH
    ushort* o216  = o116 + NH_;               // NH

    // ---- pack ----
    PKArg pk;
    pk.w[0]  = fc_W;
    pk.w[1]  = Wq;  pk.w[2]  = Wq + WSZ;
    pk.w[3]  = Wk;  pk.w[4]  = Wk + WSZ;
    pk.w[5]  = Wv;  pk.w[6]  = Wv + WSZ;
    pk.w[7]  = Wo;  pk.w[8]  = Wo + WSZ;
    pk.w[9]  = m1W; pk.w[10] = m2W;
    pk.w[11] = cW1; pk.w[12] = cW1 + WSZ;
    pk.qf = qf; pk.pl = pl;
    pk.wpk = wpk; pk.qf16 = qf16;
    pk.dist = dist; pk.dwraw = dwraw; pk.inv_cs = inv_cs;
    pack_kernel<<<232, 256, 0, stream>>>(pk);

    const GB gzb = {nullptr, nullptr, nullptr, nullptr, nullptr};

    // fc: x = relu(qf @ fcW + fcb), write f32 + bf16
    gemm_bf<<<32, 256, 0, stream>>>(
        GB{qf16, wpk + 0 * WSZ, fc_b, x, x16}, gzb, gzb, 1);

    for (int L = 0; L < 2; ++L) {
        const ushort* wq = wpk + (1 + L) * WSZ;
        const ushort* wk = wpk + (3 + L) * WSZ;
        const ushort* wv = wpk + (5 + L) * WSZ;
        const ushort* wo = wpk + (7 + L) * WSZ;

        gemm_bf<<<96, 256, 0, stream>>>(
            GB{x16, wq, bq + L * HDIM, nullptr, q16},
            GB{x16, wk, bk + L * HDIM, nullptr, k16},
            GB{x16, wv, bv + L * HDIM, v, nullptr}, 0);

        qkt_bf<<<256, 256, 0, stream>>>(q16, k16, dist, dwraw, inv_cs, S);
        smpv_kernel<<<dim3(64, NHEAD), 256, 0, stream>>>(S, v, ao16);
        oprojln<<<32, 64, 0, stream>>>(
            ao16, wo, bo + L * HDIM, lng + L * HDIM, lnb + L * HDIM, x, x16);
    }

    // mlp: o1 = relu(x@m1+b1) -> o116 ; o2 = relu(x@m2+b2) -> o216
    gemm_bf<<<64, 256, 0, stream>>>(
        GB{x16, wpk + 9 * WSZ, m1b, nullptr, o116},
        GB{x16, wpk + 10 * WSZ, m2b, nullptr, o216}, gzb, 1);
    // U1 = o1@cW1a + cb1 ; U2 = o2@cW1b
    gemm_bf<<<64, 256, 0, stream>>>(
        GB{o116, wpk + 11 * WSZ, cb1, U1, nullptr},
        GB{o216, wpk + 12 * WSZ, nullptr, U2, nullptr}, gzb, 0);

    pair_cls<<<dim3(16, 16), 256, 0, stream>>>(U1, U2, cW2, cb2, out);
}

// Round 10
// 109.748 us; speedup vs baseline: 1.1662x; 1.1662x over previous
//
#include <hip/hip_runtime.h>
#include <math.h>

// ---------------------------------------------------------------------------
// SpatialProximityHead on MI355X — round 9: 11 dispatches.
// pack -> fc -> [qkv -> attn_fused(qkt+sm+pv) -> oprojln] x2 -> mlp -> U -> pair
// All matmuls MFMA bf16; qkv writes v pre-transposed (vT16) for PV B-frags.
// ---------------------------------------------------------------------------

#define NTOK 512
#define HDIM 256
#define DKH  64
#define NHEAD 4
#define TLEN 6
#define WSZ  65536
#define PSTR 520   // P_lds ushort stride

typedef __attribute__((ext_vector_type(8))) short bf16x8;
typedef __attribute__((ext_vector_type(4))) float f32x4;

__device__ __forceinline__ ushort f2bf(float f)
{
    unsigned u = __builtin_bit_cast(unsigned, f);
    u += 0x7FFFu + ((u >> 16) & 1u);     // RNE
    return (ushort)(u >> 16);
}

struct PKArg {
    const float* w[13];
    const float* qf; const float* pl;
    ushort* wpk; ushort* qf16;
    float *dist, *dwraw, *inv_cs;
};

// ---------------------------------------------------------------------------
// pack: 0-207 weight transpose tiles ([col][k] bf16), 208-223 qf->bf16,
// 224-231 dist/dwraw/inv_cs prep.  (unchanged from round 8, proven)
// ---------------------------------------------------------------------------
__global__ __launch_bounds__(256) void pack_kernel(PKArg p)
{
    __shared__ __align__(16) ushort smu[64 * 72];
    const int bid = blockIdx.x;
    const int t   = threadIdx.x;

    if (bid < 208) {
        const int mat  = bid >> 4;
        const int tile = bid & 15;
        const int k0   = (tile >> 2) * 64;
        const int c0   = (tile & 3) * 64;
        const float* W = p.w[mat];
#pragma unroll
        for (int j = 0; j < 4; ++j) {
            const int i  = t + j * 256;
            const int r  = i >> 4, c4 = i & 15;
            const float4 v4 = *(const float4*)&W[(k0 + r) * HDIM + c0 + c4 * 4];
            smu[(c4 * 4 + 0) * 72 + r] = f2bf(v4.x);
            smu[(c4 * 4 + 1) * 72 + r] = f2bf(v4.y);
            smu[(c4 * 4 + 2) * 72 + r] = f2bf(v4.z);
            smu[(c4 * 4 + 3) * 72 + r] = f2bf(v4.w);
        }
        __syncthreads();
#pragma unroll
        for (int j = 0; j < 2; ++j) {
            const int i  = t + j * 256;
            const int cr = i >> 3, kk = i & 7;
            const uint4 v = *(const uint4*)&smu[cr * 72 + kk * 8];
            *(uint4*)&p.wpk[mat * WSZ + (c0 + cr) * HDIM + k0 + kk * 8] = v;
        }
    } else if (bid < 224) {
        const int r0 = (bid - 208) * 32;
#pragma unroll
        for (int j = 0; j < 8; ++j) {
            const int i  = t + j * 256;
            const int r  = i >> 6, c4 = i & 63;
            const float4 v4 = *(const float4*)&p.qf[(r0 + r) * HDIM + c4 * 4];
            ushort4 s = {f2bf(v4.x), f2bf(v4.y), f2bf(v4.z), f2bf(v4.w)};
            *(ushort4*)&p.qf16[(r0 + r) * HDIM + c4 * 4] = s;
        }
    } else {
        float* smf = (float*)smu;
        float* qe  = smf;
        float* red = smf + 1536;
        const int item = bid - 224;
        for (int i = t; i < 512; i += 256) {
            qe[i * 3 + 0] = p.pl[i * 33 + 30];
            qe[i * 3 + 1] = p.pl[i * 33 + 31];
            qe[i * 3 + 2] = p.pl[i * 33 + 32];
        }
        __syncthreads();
        const int m   = item * 64 + (t & 63);
        const int nch = t >> 6;
        const float kx = p.pl[m * 33 + 0], ky = p.pl[m * 33 + 1], kz = p.pl[m * 33 + 2];
        float cs = 0.f;
        for (int n = nch * 128; n < nch * 128 + 128; ++n) {
            const float dx = kx - qe[n * 3 + 0];
            const float dy = ky - qe[n * 3 + 1];
            const float dz = kz - qe[n * 3 + 2];
            const float dd = sqrtf(dx * dx + dy * dy + dz * dz);
            const float w  = 1.0f / (dd + 0.01f);
            p.dist[n * NTOK + m]  = dd;
            p.dwraw[n * NTOK + m] = w;
            cs += w;
        }
        red[nch * 64 + (t & 63)] = cs;
        __syncthreads();
        if (t < 64)
            p.inv_cs[item * 64 + t] =
                1.0f / (red[t] + red[64 + t] + red[128 + t] + red[192 + t]);
    }
}

// ---------------------------------------------------------------------------
// gemm_bf: C(512x256) = A16 @ Wt([col][k]) + b.  64 blocks/problem, wave =
// 16 rows x 32 cols (256 waves = 32 rg x 8 cg). Outputs f32 / bf16 /
// bf16-transposed ([col][row], for v).
// ---------------------------------------------------------------------------
struct GB { const ushort* A16; const ushort* Wt; const float* b;
            float* C; ushort* C16; ushort* C16T; };

__global__ __launch_bounds__(256) void gemm_bf(GB g0, GB g1, GB g2, int relu)
{
    const int bid = blockIdx.x;
    const GB g = (bid < 64) ? g0 : (bid < 128) ? g1 : g2;
    const int t = threadIdx.x;
    const int wv = t >> 6, lane = t & 63;
    const int gw = (bid & 63) * 4 + wv;        // 0..255
    const int rg = gw >> 3, cg = gw & 7;       // 32 row-groups x 8 col-groups
    const int lr = lane & 15, lg = lane >> 4, lk = lg * 8;

    const ushort* Arow = g.A16 + (rg * 16 + lr) * HDIM + lk;
    const ushort* Brow = g.Wt + (cg * 32 + lr) * HDIM + lk;

    f32x4 acc[2];
    acc[0] = (f32x4){0.f, 0.f, 0.f, 0.f};
    acc[1] = (f32x4){0.f, 0.f, 0.f, 0.f};

#pragma unroll
    for (int ks = 0; ks < 8; ++ks) {
        const bf16x8 a = *(const bf16x8*)&Arow[ks * 32];
#pragma unroll
        for (int j = 0; j < 2; ++j) {
            const bf16x8 b = *(const bf16x8*)&Brow[j * 16 * HDIM + ks * 32];
            acc[j] = __builtin_amdgcn_mfma_f32_16x16x32_bf16(a, b, acc[j], 0, 0, 0);
        }
    }

    const int orow = rg * 16 + lg * 4;
#pragma unroll
    for (int j = 0; j < 2; ++j) {
        const int col = cg * 32 + j * 16 + lr;
        const float bbv = g.b ? g.b[col] : 0.f;
        float o[4];
#pragma unroll
        for (int r = 0; r < 4; ++r) {
            o[r] = acc[j][r] + bbv;
            if (relu) o[r] = fmaxf(o[r], 0.f);
            if (g.C)   g.C[(orow + r) * HDIM + col] = o[r];
            if (g.C16) g.C16[(orow + r) * HDIM + col] = f2bf(o[r]);
        }
        if (g.C16T) {
            ushort4 s = {f2bf(o[0]), f2bf(o[1]), f2bf(o[2]), f2bf(o[3])};
            *(ushort4*)&g.C16T[col * NTOK + orow] = s;
        }
    }
}

// ---------------------------------------------------------------------------
// attn_fused: per (head h, 16-row band): S = qk^T/8 + bias (MFMA, in-reg),
// cross-wave softmax (max, sum via LDS), P->bf16->LDS, PV (MFMA vs vT16),
// cross-wave combine with 1/rowsum, write ao16. 128 blocks x 256 thr.
// Wave wv owns m-range [wv*128, wv*128+128).
// ---------------------------------------------------------------------------
__global__ __launch_bounds__(256) void attn_fused(
    const ushort* __restrict__ q16, const ushort* __restrict__ k16,
    const ushort* __restrict__ vT16, const float* __restrict__ dist,
    const float* __restrict__ dwraw, const float* __restrict__ inv_cs,
    ushort* __restrict__ ao16)
{
    __shared__ __align__(16) ushort P_lds[16 * PSTR];   // 16.6 KB
    __shared__ __align__(16) float exch[4][16][64];     // 16 KB
    __shared__ float rmax[4][16];
    __shared__ float psums[4][16];

    const int bid = blockIdx.x;
    const int h  = bid >> 5;
    const int n0 = (bid & 31) * 16;
    const int t  = threadIdx.x;
    const int wv = t >> 6, lane = t & 63;
    const int lr = lane & 15, lg = lane >> 4, lk = lg * 8;
    const int mW = wv * 128;

    // ---- S = Q @ K^T (16 x 128 per wave) ----
    const ushort* Qrow = q16 + (n0 + lr) * HDIM + h * DKH + lk;
    const bf16x8 a0 = *(const bf16x8*)&Qrow[0];
    const bf16x8 a1 = *(const bf16x8*)&Qrow[32];

    f32x4 accs[8];
#pragma unroll
    for (int cg = 0; cg < 8; ++cg) accs[cg] = (f32x4){0.f, 0.f, 0.f, 0.f};
#pragma unroll
    for (int cg = 0; cg < 8; ++cg) {
        const ushort* Brow = k16 + (mW + cg * 16 + lr) * HDIM + h * DKH + lk;
        accs[cg] = __builtin_amdgcn_mfma_f32_16x16x32_bf16(
            a0, *(const bf16x8*)&Brow[0], accs[cg], 0, 0, 0);
        accs[cg] = __builtin_amdgcn_mfma_f32_16x16x32_bf16(
            a1, *(const bf16x8*)&Brow[32], accs[cg], 0, 0, 0);
    }

    // ---- scale + bias ----
    float s[8][4];
#pragma unroll
    for (int cg = 0; cg < 8; ++cg) {
        const int m = mW + cg * 16 + lr;
        const float ic = (h == 0) ? inv_cs[m] : 0.f;
#pragma unroll
        for (int rg = 0; rg < 4; ++rg) {
            const int n = n0 + lg * 4 + rg;
            float b = 0.f;
            if (h == 0)      b = dwraw[n * NTOK + m] * ic;
            else if (h == 1) b = -dist[n * NTOK + m];
            s[cg][rg] = accs[cg][rg] * 0.125f + b;
        }
    }

    // ---- row max (wave-partial -> LDS -> global) ----
    float mx[4];
#pragma unroll
    for (int rg = 0; rg < 4; ++rg) {
        float m = s[0][rg];
#pragma unroll
        for (int cg = 1; cg < 8; ++cg) m = fmaxf(m, s[cg][rg]);
#pragma unroll
        for (int o = 1; o < 16; o <<= 1) m = fmaxf(m, __shfl_xor(m, o));
        mx[rg] = m;
    }
    if (lr == 0)
#pragma unroll
        for (int rg = 0; rg < 4; ++rg) rmax[wv][lg * 4 + rg] = mx[rg];
    __syncthreads();
    float mxf[4];
#pragma unroll
    for (int rg = 0; rg < 4; ++rg) {
        const int row = lg * 4 + rg;
        mxf[rg] = fmaxf(fmaxf(rmax[0][row], rmax[1][row]),
                        fmaxf(rmax[2][row], rmax[3][row]));
    }

    // ---- exp, partial sums, P -> LDS (bf16) ----
    float ps[4] = {0.f, 0.f, 0.f, 0.f};
#pragma unroll
    for (int cg = 0; cg < 8; ++cg)
#pragma unroll
        for (int rg = 0; rg < 4; ++rg) {
            const float e = __expf(s[cg][rg] - mxf[rg]);
            ps[rg] += e;
            P_lds[(lg * 4 + rg) * PSTR + mW + cg * 16 + lr] = f2bf(e);
        }
#pragma unroll
    for (int rg = 0; rg < 4; ++rg) {
#pragma unroll
        for (int o = 1; o < 16; o <<= 1) ps[rg] += __shfl_xor(ps[rg], o);
    }
    if (lr == 0)
#pragma unroll
        for (int rg = 0; rg < 4; ++rg) psums[wv][lg * 4 + rg] = ps[rg];
    __syncthreads();

    // ---- PV: wave's k-range = its own m-range ----
    f32x4 acco[4];
#pragma unroll
    for (int db = 0; db < 4; ++db) acco[db] = (f32x4){0.f, 0.f, 0.f, 0.f};
#pragma unroll
    for (int c = 0; c < 4; ++c) {
        const bf16x8 pa = *(const bf16x8*)&P_lds[lr * PSTR + mW + c * 32 + lk];
#pragma unroll
        for (int db = 0; db < 4; ++db) {
            const bf16x8 b = *(const bf16x8*)
                &vT16[(h * DKH + db * 16 + lr) * NTOK + mW + c * 32 + lk];
            acco[db] = __builtin_amdgcn_mfma_f32_16x16x32_bf16(pa, b, acco[db], 0, 0, 0);
        }
    }
#pragma unroll
    for (int db = 0; db < 4; ++db)
#pragma unroll
        for (int rg = 0; rg < 4; ++rg)
            exch[wv][lg * 4 + rg][db * 16 + lr] = acco[db][rg];
    __syncthreads();

    // ---- combine + 1/rowsum + store ----
    {
        const int r = t >> 4, d4 = t & 15;
        f32x4 sum = *(const f32x4*)&exch[0][r][d4 * 4];
        sum += *(const f32x4*)&exch[1][r][d4 * 4];
        sum += *(const f32x4*)&exch[2][r][d4 * 4];
        sum += *(const f32x4*)&exch[3][r][d4 * 4];
        const float inv = 1.0f / (psums[0][r] + psums[1][r] + psums[2][r] + psums[3][r]);
        ushort4 o = {f2bf(sum.x * inv), f2bf(sum.y * inv),
                     f2bf(sum.z * inv), f2bf(sum.w * inv)};
        *(ushort4*)&ao16[(n0 + r) * HDIM + h * DKH + d4 * 4] = o;
    }
}

// ---------------------------------------------------------------------------
// oprojln: block = 16 rows, 256 thr; wave wv = cols wv*64..+64.
// y = ao16@WoT + bo + x; x = LN(y)*g + b; writes x f32 + x16 bf16.
// ---------------------------------------------------------------------------
__global__ __launch_bounds__(256) void oprojln(
    const ushort* __restrict__ ao16, const ushort* __restrict__ WoT,
    const float* __restrict__ bo, const float* __restrict__ g,
    const float* __restrict__ bb, float* __restrict__ x,
    ushort* __restrict__ x16)
{
    __shared__ float red[4][16];

    const int n0 = blockIdx.x * 16;
    const int t  = threadIdx.x;
    const int wv = t >> 6, lane = t & 63;
    const int lr = lane & 15, lg = lane >> 4, lk = lg * 8;

    const ushort* Arow = ao16 + (n0 + lr) * HDIM + lk;

    f32x4 acc[4];
#pragma unroll
    for (int j = 0; j < 4; ++j) acc[j] = (f32x4){0.f, 0.f, 0.f, 0.f};

#pragma unroll
    for (int ks = 0; ks < 8; ++ks) {
        const bf16x8 a = *(const bf16x8*)&Arow[ks * 32];
#pragma unroll
        for (int j = 0; j < 4; ++j) {
            const bf16x8 b = *(const bf16x8*)
                &WoT[(wv * 64 + j * 16 + lr) * HDIM + ks * 32 + lk];
            acc[j] = __builtin_amdgcn_mfma_f32_16x16x32_bf16(a, b, acc[j], 0, 0, 0);
        }
    }

    // y = acc + bo + x
#pragma unroll
    for (int j = 0; j < 4; ++j) {
        const int col = wv * 64 + j * 16 + lr;
        const float bc = bo[col];
#pragma unroll
        for (int rg = 0; rg < 4; ++rg)
            acc[j][rg] += bc + x[(n0 + lg * 4 + rg) * HDIM + col];
    }

    // mean
    float sm[4];
#pragma unroll
    for (int rg = 0; rg < 4; ++rg) {
        float s = 0.f;
#pragma unroll
        for (int j = 0; j < 4; ++j) s += acc[j][rg];
#pragma unroll
        for (int o = 1; o < 16; o <<= 1) s += __shfl_xor(s, o);
        sm[rg] = s;
    }
    if (lr == 0)
#pragma unroll
        for (int rg = 0; rg < 4; ++rg) red[wv][lg * 4 + rg] = sm[rg];
    __syncthreads();
    float mean[4];
#pragma unroll
    for (int rg = 0; rg < 4; ++rg) {
        const int row = lg * 4 + rg;
        mean[rg] = (red[0][row] + red[1][row] + red[2][row] + red[3][row]) * (1.f / 256.f);
    }
    __syncthreads();

    // var
#pragma unroll
    for (int rg = 0; rg < 4; ++rg) {
        float s2 = 0.f;
#pragma unroll
        for (int j = 0; j < 4; ++j) {
            const float c = acc[j][rg] - mean[rg];
            s2 += c * c;
        }
#pragma unroll
        for (int o = 1; o < 16; o <<= 1) s2 += __shfl_xor(s2, o);
        sm[rg] = s2;
    }
    if (lr == 0)
#pragma unroll
        for (int rg = 0; rg < 4; ++rg) red[wv][lg * 4 + rg] = sm[rg];
    __syncthreads();
    float rstd[4];
#pragma unroll
    for (int rg = 0; rg < 4; ++rg) {
        const int row = lg * 4 + rg;
        const float var = (red[0][row] + red[1][row] + red[2][row] + red[3][row]) * (1.f / 256.f);
        rstd[rg] = rsqrtf(var + 1e-5f);
    }

#pragma unroll
    for (int j = 0; j < 4; ++j) {
        const int col = wv * 64 + j * 16 + lr;
        const float gg = g[col], bv = bb[col];
#pragma unroll
        for (int rg = 0; rg < 4; ++rg) {
            const int row = n0 + lg * 4 + rg;
            const float o = (acc[j][rg] - mean[rg]) * rstd[rg] * gg + bv;
            x[row * HDIM + col]   = o;
            x16[row * HDIM + col] = f2bf(o);
        }
    }
}

// ---------------------------------------------------------------------------
// pair_cls: 32x32 tile, 2x2 per thread, TL copies. (f32 inputs, proven)
// ---------------------------------------------------------------------------
__global__ __launch_bounds__(256) void pair_cls(const float* __restrict__ U1,
                                                const float* __restrict__ U2,
                                                const float* __restrict__ W2,
                                                const float* __restrict__ b2,
                                                float* __restrict__ out)
{
    __shared__ __align__(16) float u1s[32][260];
    __shared__ __align__(16) float u2s[32][260];
    __shared__ __align__(16) float w2s[256];
    const int t  = threadIdx.x;
    const int n0 = blockIdx.y * 32, m0 = blockIdx.x * 32;

    for (int i = t; i < 32 * 64; i += 256) {
        const int r = i >> 6, c4 = i & 63;
        *(float4*)&u1s[r][c4 * 4] = *(const float4*)&U1[(n0 + r) * HDIM + c4 * 4];
        *(float4*)&u2s[r][c4 * 4] = *(const float4*)&U2[(m0 + r) * HDIM + c4 * 4];
    }
    if (t < 64) *(float4*)&w2s[t * 4] = *(const float4*)&W2[t * 4];
    __syncthreads();

    const int tx = t & 15, ty = t >> 4;
    float acc[2][2] = {};
    for (int h4 = 0; h4 < 64; ++h4) {
        const float4 a0 = *(const float4*)&u1s[ty * 2][h4 * 4];
        const float4 a1 = *(const float4*)&u1s[ty * 2 + 1][h4 * 4];
        const float4 b0 = *(const float4*)&u2s[tx * 2][h4 * 4];
        const float4 b1 = *(const float4*)&u2s[tx * 2 + 1][h4 * 4];
        const float4 w  = *(const float4*)&w2s[h4 * 4];
#define RT(A, B) fmaxf((A) + (B), 0.f)
        acc[0][0] += RT(a0.x,b0.x)*w.x + RT(a0.y,b0.y)*w.y + RT(a0.z,b0.z)*w.z + RT(a0.w,b0.w)*w.w;
        acc[0][1] += RT(a0.x,b1.x)*w.x + RT(a0.y,b1.y)*w.y + RT(a0.z,b1.z)*w.z + RT(a0.w,b1.w)*w.w;
        acc[1][0] += RT(a1.x,b0.x)*w.x + RT(a1.y,b0.y)*w.y + RT(a1.z,b0.z)*w.z + RT(a1.w,b0.w)*w.w;
        acc[1][1] += RT(a1.x,b1.x)*w.x + RT(a1.y,b1.y)*w.y + RT(a1.z,b1.z)*w.z + RT(a1.w,b1.w)*w.w;
#undef RT
    }
    const float bbv = b2[0];
#pragma unroll
    for (int ii = 0; ii < 2; ++ii)
#pragma unroll
        for (int jj = 0; jj < 2; ++jj) {
            const float val = acc[ii][jj] + bbv;
            const int n = n0 + ty * 2 + ii;
            const int m = m0 + tx * 2 + jj;
#pragma unroll
            for (int tl = 0; tl < TLEN; ++tl)
                out[tl * NTOK * NTOK + n * NTOK + m] = val;
        }
}

// ---------------------------------------------------------------------------
extern "C" void kernel_launch(void* const* d_in, const int* in_sizes, int n_in,
                              void* d_out, int out_size, void* d_ws, size_t ws_size,
                              hipStream_t stream)
{
    const float* hs   = (const float*)d_in[0];
    const float* qf   = hs + 5 * NTOK * HDIM;
    const float* alp  = (const float*)d_in[1];
    const float* pl   = alp + 5 * NTOK * 33;
    const float* fc_W = (const float*)d_in[2];
    const float* fc_b = (const float*)d_in[3];
    const float* Wq   = (const float*)d_in[4];
    const float* bq   = (const float*)d_in[5];
    const float* Wk   = (const float*)d_in[6];
    const float* bk   = (const float*)d_in[7];
    const float* Wv   = (const float*)d_in[8];
    const float* bv   = (const float*)d_in[9];
    const float* Wo   = (const float*)d_in[10];
    const float* bo   = (const float*)d_in[11];
    const float* lng  = (const float*)d_in[12];
    const float* lnb  = (const float*)d_in[13];
    const float* m1W  = (const float*)d_in[14];
    const float* m1b  = (const float*)d_in[15];
    const float* m2W  = (const float*)d_in[16];
    const float* m2b  = (const float*)d_in[17];
    const float* cW1  = (const float*)d_in[18];
    const float* cb1  = (const float*)d_in[19];
    const float* cW2  = (const float*)d_in[20];
    const float* cb2  = (const float*)d_in[21];
    float* out = (float*)d_out;

    const int NN  = NTOK * NTOK;
    const int NH_ = NTOK * HDIM;
    float* ws     = (float*)d_ws;
    float* dist   = ws;                       // NN
    float* dwraw  = ws + NN;                  // NN
    float* inv_cs = ws + 2 * NN;              // 512
    float* x      = ws + 2 * NN + 512;        // NH
    float* U1     = x + NH_;                  // NH
    float* U2     = U1 + NH_;                 // NH
    ushort* u16   = (ushort*)(U2 + NH_);
    ushort* wpk   = u16;                      // 13 * WSZ
    ushort* qf16  = wpk + 13 * WSZ;           // NH
    ushort* x16   = qf16 + NH_;               // NH
    ushort* q16   = x16 + NH_;                // NH
    ushort* k16   = q16 + NH_;                // NH
    ushort* vT16  = k16 + NH_;                // NH ([d][m])
    ushort* ao16  = vT16 + NH_;               // NH
    ushort* o116  = ao16 + NH_;               // NH
    ushort* o216  = o116 + NH_;               // NH

    PKArg pk;
    pk.w[0]  = fc_W;
    pk.w[1]  = Wq;  pk.w[2]  = Wq + WSZ;
    pk.w[3]  = Wk;  pk.w[4]  = Wk + WSZ;
    pk.w[5]  = Wv;  pk.w[6]  = Wv + WSZ;
    pk.w[7]  = Wo;  pk.w[8]  = Wo + WSZ;
    pk.w[9]  = m1W; pk.w[10] = m2W;
    pk.w[11] = cW1; pk.w[12] = cW1 + WSZ;
    pk.qf = qf; pk.pl = pl;
    pk.wpk = wpk; pk.qf16 = qf16;
    pk.dist = dist; pk.dwraw = dwraw; pk.inv_cs = inv_cs;
    pack_kernel<<<232, 256, 0, stream>>>(pk);

    const GB gzb = {nullptr, nullptr, nullptr, nullptr, nullptr, nullptr};

    // fc: x = relu(qf @ fcW + fcb) -> x f32 + x16
    gemm_bf<<<64, 256, 0, stream>>>(
        GB{qf16, wpk + 0 * WSZ, fc_b, x, x16, nullptr}, gzb, gzb, 1);

    for (int L = 0; L < 2; ++L) {
        const ushort* wq = wpk + (1 + L) * WSZ;
        const ushort* wk = wpk + (3 + L) * WSZ;
        const ushort* wv = wpk + (5 + L) * WSZ;
        const ushort* wo = wpk + (7 + L) * WSZ;

        gemm_bf<<<192, 256, 0, stream>>>(
            GB{x16, wq, bq + L * HDIM, nullptr, q16, nullptr},
            GB{x16, wk, bk + L * HDIM, nullptr, k16, nullptr},
            GB{x16, wv, bv + L * HDIM, nullptr, nullptr, vT16}, 0);

        attn_fused<<<128, 256, 0, stream>>>(
            q16, k16, vT16, dist, dwraw, inv_cs, ao16);

        oprojln<<<32, 256, 0, stream>>>(
            ao16, wo, bo + L * HDIM, lng + L * HDIM, lnb + L * HDIM, x, x16);
    }

    // mlp: o1/o2 (bf16 only)
    gemm_bf<<<128, 256, 0, stream>>>(
        GB{x16, wpk + 9 * WSZ, m1b, nullptr, o116, nullptr},
        GB{x16, wpk + 10 * WSZ, m2b, nullptr, o216, nullptr}, gzb, 1);
    // U1 = o1@cW1a + cb1 ; U2 = o2@cW1b
    gemm_bf<<<128, 256, 0, stream>>>(
        GB{o116, wpk + 11 * WSZ, cb1, U1, nullptr, nullptr},
        GB{o216, wpk + 12 * WSZ, nullptr, U2, nullptr, nullptr}, gzb, 0);

    pair_cls<<<dim3(16, 16), 256, 0, stream>>>(U1, U2, cW2, cb2, out);
}